// Round 13
// baseline (89.010 us; speedup 1.0000x reference)
//
#include <hip/hip_runtime.h>

typedef _Float16 half8 __attribute__((ext_vector_type(8)));
typedef float f32x4 __attribute__((ext_vector_type(4)));

#define B_DIM 512
#define C_DIM 512
#define BC (B_DIM * C_DIM)

constexpr int NCH[6]      = {6, 5, 5, 4, 4, 3};
constexpr int BASE[6]     = {0, 6, 21, 46, 74, 110};   // x BC elements
constexpr int FIRST_L1[6] = {0, 1, 1, 2, 2, 3};

// triangular pair decode: p -> (a, b) with a<=b
constexpr int pair_a(int p, int d) {
    int a = 0, rem = p;
    while (rem >= d - a) { rem -= d - a; ++a; }
    return a;
}
constexpr int pair_b(int p, int d) {
    int a = 0, rem = p;
    while (rem >= d - a) { rem -= d - a; ++a; }
    return a + rem;
}

struct PrepArgs {
    const float* cg[5][6];   // [l1-1][L]
    int l1[21], ks[21], nt[21];
};

// Build fp16 B-fragments in exact MFMA lane layout, zero-padded.
// frag elem (lane, j): n = nt*16 + (lane&15), k = (lane>>4)*8 + j, p = ks*32 + k.
__global__ void prep_frags(PrepArgs pa, _Float16* __restrict__ wsf) {
    const int f  = blockIdx.x;                 // global frag id, grid = 21
    const int l1 = pa.l1[f], ks = pa.ks[f], nt = pa.nt[f];
    const int d = 2 * l1 + 1, NP = d * (d + 1) / 2;
    const int Lmax = (2 * l1 < 5) ? 2 * l1 : 5;
    const int Ntot = (Lmax + 1) * (Lmax + 1);
    const int e = (int)threadIdx.x;            // 0..511
    const int lane = e >> 3, j = e & 7;
    const int n = nt * 16 + (lane & 15);
    const int p = ks * 32 + (lane >> 4) * 8 + j;
    float v = 0.f;
    if (n < Ntot && p < NP) {
        int L = 0;
        while ((L + 1) * (L + 1) <= n) ++L;
        const int M = n - L * L;
        int a = 0, rem = p;
        while (rem >= d - a) { rem -= d - a; ++a; }
        const int bb = a + rem;
        const float* cg = pa.cg[l1 - 1][L];
        v = cg[(M * d + a) * d + bb];
        if (a != bb) v += cg[(M * d + bb) * d + a];
    }
    wsf[(size_t)f * 512 + e] = (_Float16)v;
}

template <int L1>
__device__ __forceinline__ void tp_mfma(const float* __restrict__ x,
                                        const _Float16* __restrict__ wsf,
                                        float* __restrict__ out,
                                        int blk, _Float16* __restrict__ Alds,
                                        float* __restrict__ os) {
    constexpr int d    = 2 * L1 + 1;
    constexpr int NP   = d * (d + 1) / 2;
    constexpr int Lmax = (2 * L1 < 5) ? 2 * L1 : 5;
    constexpr int Ntot = (Lmax + 1) * (Lmax + 1);
    constexpr int KS   = (NP + 31) / 32;       // K-steps of 32
    constexpr int NT   = (Ntot + 15) / 16;     // N-tiles of 16
    constexpr int AST  = 34;                   // A row stride in f16 (68 B; 17 banks)
    constexpr int OST  = 36;                   // os row stride in f32 (col = n)

    const int tid = (int)threadIdx.x, lane = tid & 63, w = tid >> 6;
    const int t0 = blk << 8;                   // 256 rows per block
    const int b = blk >> 1, i0 = (blk & 1) << 8;

    // per-thread x row (round-6/9 verified direct loads)
    float xv[d];
    const float* xp = x + (size_t)(t0 + tid) * d;
#pragma unroll
    for (int m = 0; m < d; ++m) xv[m] = xp[m];

    const f32x4 zero = {0.f, 0.f, 0.f, 0.f};
    f32x4 acc[4][NT];
#pragma unroll
    for (int q = 0; q < 4; ++q)
#pragma unroll
        for (int nt = 0; nt < NT; ++nt) acc[q][nt] = zero;

    // ---- K-loop: VERBATIM round-6/9-verified pattern (AST constant only) ----
#pragma unroll
    for (int ks = 0; ks < KS; ++ks) {
        // B fragments for this K-step (register-only; low VGPR pressure)
        half8 bf[NT];
#pragma unroll
        for (int nt = 0; nt < NT; ++nt)
            bf[nt] = *(const half8*)(wsf + ((size_t)ks * NT + nt) * 512 + lane * 8);

        half8 ph[4];
#pragma unroll
        for (int g = 0; g < 4; ++g) {
#pragma unroll
            for (int j = 0; j < 8; ++j) {
                const int p = ks * 32 + g * 8 + j;
                float v = 0.f;
                if (p < NP) v = xv[pair_a(p, d)] * xv[pair_b(p, d)];
                ph[g][j] = (_Float16)v;
            }
        }
        // write own row; read wave-own rows (verified in-wave in-order pattern)
        _Float16* ar = Alds + tid * AST;
#pragma unroll
        for (int g = 0; g < 4; ++g) *(half8*)(ar + g * 8) = ph[g];
#pragma unroll
        for (int q = 0; q < 4; ++q) {
            const int row = (w * 4 + q) * 16 + (lane & 15);
            const half8 af = *(const half8*)(Alds + row * AST + (lane >> 4) * 8);
#pragma unroll
            for (int nt = 0; nt < NT; ++nt)
                acc[q][nt] = __builtin_amdgcn_mfma_f32_16x16x32_f16(
                    af, bf[nt], acc[q][nt], 0, 0, 0);
        }
    }

    // ---- epilogue: scatter ALL -> ONE barrier -> copy ALL ----
    // Barrier sits BEFORE any epilogue global store: its implicit vmcnt(0)
    // waits only on long-finished loads; stores drain at kernel end.
    const int rb = w * 64 + ((lane >> 4) << 2);   // D-row base (r8/r9 verified)
#pragma unroll
    for (int q = 0; q < 4; ++q) {
#pragma unroll
        for (int nt = 0; nt < NT; ++nt) {
            const int n = nt * 16 + (lane & 15);  // col = n = L^2 + M directly
            if (n < Ntot) {
                const int row = rb + q * 16;
#pragma unroll
                for (int r = 0; r < 4; ++r)
                    os[(row + r) * OST + n] = acc[q][nt][r];
            }
        }
    }

    __syncthreads();   // the ONLY epilogue barrier: scatter -> copy fence

#pragma unroll
    for (int L = 0; L <= Lmax; ++L) {
        const int L0 = L * L;
        const int stride = 2 * L + 1;
        const int chunk = L1 - FIRST_L1[L];
        float* __restrict__ dst = out + (size_t)BASE[L] * BC +
            ((size_t)(b * NCH[L] + chunk) * C_DIM + i0) * stride;
#pragma unroll
        for (int k0 = 0; k0 < 256 * 11; k0 += 256) {
            const int k = k0 + tid;
            if (k < 256 * stride) {
                const int row = k / stride;       // constexpr stride: magic-mul
                const int m = k - row * stride;
                dst[k] = os[row * OST + L0 + m];
            }
        }
    }
}

__global__ __launch_bounds__(256) void tp_all(
    const float* __restrict__ x0, const float* __restrict__ x1,
    const float* __restrict__ x2, const float* __restrict__ x3,
    const float* __restrict__ x4, const float* __restrict__ x5,
    const float* __restrict__ cg00, const _Float16* __restrict__ wsf,
    float* __restrict__ out) {
    __shared__ _Float16 Alds[256 * 34];              // 17408 B (K-loop A tiles)
    __shared__ __align__(16) float os[256 * 36];     // 36864 B (epilogue bounce)
    const int part = (int)blockIdx.x >> 10;    // 1024 blocks per part, heavy first
    const int blk  = (int)blockIdx.x & 1023;
    switch (part) {
        case 0: tp_mfma<5>(x5, wsf + 12 * 512, out, blk, Alds, os); break;
        case 1: tp_mfma<4>(x4, wsf + 6 * 512,  out, blk, Alds, os); break;
        case 2: tp_mfma<3>(x3, wsf + 3 * 512,  out, blk, Alds, os); break;
        case 3: tp_mfma<2>(x2, wsf + 1 * 512,  out, blk, Alds, os); break;
        case 4: tp_mfma<1>(x1, wsf + 0,        out, blk, Alds, os); break;
        default: {                              // l1 = 0: out = c00 * x0^2
            const int t = (blk << 8) + (int)threadIdx.x;
            const float v = x0[t];
            const int b = t >> 9, i = t & 511;
            out[(size_t)b * 3072 + i] = cg00[0] * v * v;
        } break;
    }
}

extern "C" void kernel_launch(void* const* d_in, const int* in_sizes, int n_in,
                              void* d_out, int out_size, void* d_ws, size_t ws_size,
                              hipStream_t stream) {
    (void)in_sizes; (void)n_in; (void)out_size; (void)ws_size;

    PrepArgs pa{};
    int idx = 6;
    for (int l1 = 0; l1 <= 5; ++l1) {
        const int Lmax = (2 * l1 < 5) ? 2 * l1 : 5;
        for (int L = 0; L <= Lmax; ++L) {
            if (l1 >= 1) pa.cg[l1 - 1][L] = (const float*)d_in[idx];
            ++idx;
        }
    }
    int f = 0;
    for (int l1 = 1; l1 <= 5; ++l1) {
        const int d = 2 * l1 + 1, NP = d * (d + 1) / 2;
        const int Lmax = (2 * l1 < 5) ? 2 * l1 : 5;
        const int Ntot = (Lmax + 1) * (Lmax + 1);
        const int KS = (NP + 31) / 32, NT = (Ntot + 15) / 16;
        for (int ks = 0; ks < KS; ++ks)
            for (int nt = 0; nt < NT; ++nt) {
                pa.l1[f] = l1; pa.ks[f] = ks; pa.nt[f] = nt; ++f;
            }
    }
    // f == 21 frags -> 21.5 KB fp16 table in ws

    hipLaunchKernelGGL(prep_frags, dim3(21), dim3(512), 0, stream,
                       pa, (_Float16*)d_ws);
    hipLaunchKernelGGL(tp_all, dim3(6 * 1024), dim3(256), 0, stream,
                       (const float*)d_in[0], (const float*)d_in[1],
                       (const float*)d_in[2], (const float*)d_in[3],
                       (const float*)d_in[4], (const float*)d_in[5],
                       (const float*)d_in[6], (const _Float16*)d_ws,
                       (float*)d_out);
}